// Round 3
// baseline (839.099 us; speedup 1.0000x reference)
//
#include <hip/hip_runtime.h>

#define D 128
#define NNODES 50000
#define NEDGES 800000
#define NGRAPH 512
#define NOUT 64
#define EPSBN 1e-5f

// ---------------------------------------------------------------- utilities
__global__ __launch_bounds__(256) void k_zero_i32(int* __restrict__ p, int n) {
    int i = blockIdx.x * 256 + threadIdx.x;
    if (i < n) p[i] = 0;
}

// ---------------------------------------------------------------- CSR build
__global__ __launch_bounds__(256) void k_count(const int* __restrict__ ei, int* __restrict__ deg) {
    int e = blockIdx.x * 256 + threadIdx.x;
    if (e < NEDGES) atomicAdd(&deg[ei[NEDGES + e]], 1);  // dst = ei[1][e]
}

// single-block scan over all NNODES degrees -> offsets (incl+1) and cursor (excl)
__global__ __launch_bounds__(1024) void k_scan_all(const int* __restrict__ deg,
                                                   int* __restrict__ offs,
                                                   int* __restrict__ cursor) {
    __shared__ int s[1024];
    const int T = 1024;
    const int C = (NNODES + T - 1) / T;  // 49
    const int t = threadIdx.x;
    const int beg = t * C;
    const int end = (beg + C < NNODES) ? beg + C : NNODES;
    int sum = 0;
    for (int i = beg; i < end; ++i) sum += deg[i];
    s[t] = sum;
    __syncthreads();
    #pragma unroll
    for (int off = 1; off < T; off <<= 1) {
        int v = (t >= off) ? s[t - off] : 0;
        __syncthreads();
        s[t] += v;
        __syncthreads();
    }
    int run = s[t] - sum;  // exclusive prefix of this thread's chunk
    for (int i = beg; i < end; ++i) {
        int d = deg[i];
        cursor[i] = run;
        offs[i + 1] = run + d;
        run += d;
    }
    if (t == 0) offs[0] = 0;
}

__global__ __launch_bounds__(256) void k_fill(const int* __restrict__ ei, int* __restrict__ cursor,
                                              int* __restrict__ esrc) {
    int e = blockIdx.x * 256 + threadIdx.x;
    if (e < NEDGES) {
        int dst = ei[NEDGES + e];
        int pos = atomicAdd(&cursor[dst], 1);
        esrc[pos] = ei[e];  // src = ei[0][e]
    }
}

// ---------------------------------------------------------------- mean aggregation (gather)
// one wave per node; lanes 0-31 take even-offset edges, 32-63 odd, float4 each;
// 2-deep unroll -> 4 gather rows in flight; cross-half combine via shfl_xor(32)
__global__ __launch_bounds__(256) void k_aggregate(const float* __restrict__ hin,
                                                   const int* __restrict__ offs,
                                                   const int* __restrict__ esrc,
                                                   float* __restrict__ agg) {
    const int wid = threadIdx.x >> 6;
    const int lane = threadIdx.x & 63;
    const int node = blockIdx.x * 4 + wid;
    if (node >= NNODES) return;
    const int beg = offs[node];
    const int end = offs[node + 1];
    const int lh = lane >> 5;        // half id
    const int c4 = (lane & 31) * 4;  // feature quad
    float4 a0 = {0.f, 0.f, 0.f, 0.f};
    float4 a1 = {0.f, 0.f, 0.f, 0.f};
    int e = beg + lh;
    for (; e + 4 <= end; e += 4) {   // this half: edges e and e+2
        int s0 = esrc[e], s1 = esrc[e + 2];
        float4 v0 = *reinterpret_cast<const float4*>(&hin[s0 * D + c4]);
        float4 v1 = *reinterpret_cast<const float4*>(&hin[s1 * D + c4]);
        a0.x += v0.x; a0.y += v0.y; a0.z += v0.z; a0.w += v0.w;
        a1.x += v1.x; a1.y += v1.y; a1.z += v1.z; a1.w += v1.w;
    }
    for (; e < end; e += 2) {
        int s0 = esrc[e];
        float4 v0 = *reinterpret_cast<const float4*>(&hin[s0 * D + c4]);
        a0.x += v0.x; a0.y += v0.y; a0.z += v0.z; a0.w += v0.w;
    }
    a0.x += a1.x; a0.y += a1.y; a0.z += a1.z; a0.w += a1.w;
    // cross-half reduce (lane i += lane i^32)
    float ox = a0.x + __shfl_xor(a0.x, 32);
    float oy = a0.y + __shfl_xor(a0.y, 32);
    float oz = a0.z + __shfl_xor(a0.z, 32);
    float ow = a0.w + __shfl_xor(a0.w, 32);
    if (lane < 32) {
        int dg = end - beg;
        float inv = 1.f / (float)(dg > 0 ? dg : 1);
        float4 o; o.x = ox * inv; o.y = oy * inv; o.z = oz * inv; o.w = ow * inv;
        *reinterpret_cast<float4*>(&agg[node * D + c4]) = o;
    }
}

// ---------------------------------------------------------------- fused dual-GEMM + BN + ReLU
// hout = relu( BN( agg@Wl + bl + hin@Wr ) ), tile 64 rows x 128 cols, BK=32
__global__ __launch_bounds__(256) void k_sage_gemm(const float* __restrict__ agg,
                                                   const float* __restrict__ hin,
                                                   const float* __restrict__ Wl,
                                                   const float* __restrict__ Wr,
                                                   const float* __restrict__ bl,
                                                   const float* __restrict__ gamma,
                                                   const float* __restrict__ beta,
                                                   const float* __restrict__ rmean,
                                                   const float* __restrict__ rvar,
                                                   float* __restrict__ hout, int nrows) {
    __shared__ float At_a[32][68];   // transposed A chunks: [k][row], pad 68 keeps 16B align
    __shared__ float At_h[32][68];
    __shared__ float Ws_l[32][D];
    __shared__ float Ws_r[32][D];

    const int tid = threadIdx.x;
    const int tc4 = (tid & 31) * 4;  // output cols tc4..tc4+3
    const int tr8 = (tid >> 5) * 8;  // output rows tr8..tr8+7 (within tile)
    const int row0 = blockIdx.x * 64;

    float acc[8][4];
    #pragma unroll
    for (int r = 0; r < 8; ++r)
        #pragma unroll
        for (int c = 0; c < 4; ++c) acc[r][c] = 0.f;

    for (int kc = 0; kc < 4; ++kc) {
        const int k0 = kc * 32;
        #pragma unroll
        for (int t = 0; t < 2; ++t) {
            int l = tid + t * 256;          // 0..511
            int ar = l >> 3;                // 0..63 row in tile
            int c4 = l & 7;                 // 0..7 k-quad
            int grow = row0 + ar;
            if (grow >= nrows) grow = nrows - 1;
            const float4 va = *reinterpret_cast<const float4*>(&agg[grow * D + k0 + c4 * 4]);
            const float4 vh = *reinterpret_cast<const float4*>(&hin[grow * D + k0 + c4 * 4]);
            At_a[c4 * 4 + 0][ar] = va.x; At_a[c4 * 4 + 1][ar] = va.y;
            At_a[c4 * 4 + 2][ar] = va.z; At_a[c4 * 4 + 3][ar] = va.w;
            At_h[c4 * 4 + 0][ar] = vh.x; At_h[c4 * 4 + 1][ar] = vh.y;
            At_h[c4 * 4 + 2][ar] = vh.z; At_h[c4 * 4 + 3][ar] = vh.w;
        }
        #pragma unroll
        for (int t = 0; t < 4; ++t) {
            int l = tid + t * 256;          // 0..1023
            int wr_ = l >> 5;               // 0..31 (k within chunk)
            int wc = (l & 31) * 4;          // col
            *reinterpret_cast<float4*>(&Ws_l[wr_][wc]) =
                *reinterpret_cast<const float4*>(&Wl[(k0 + wr_) * D + wc]);
            *reinterpret_cast<float4*>(&Ws_r[wr_][wc]) =
                *reinterpret_cast<const float4*>(&Wr[(k0 + wr_) * D + wc]);
        }
        __syncthreads();
        #pragma unroll
        for (int k = 0; k < 32; ++k) {
            const float4 aa0 = *reinterpret_cast<const float4*>(&At_a[k][tr8]);
            const float4 aa1 = *reinterpret_cast<const float4*>(&At_a[k][tr8 + 4]);
            const float4 ah0 = *reinterpret_cast<const float4*>(&At_h[k][tr8]);
            const float4 ah1 = *reinterpret_cast<const float4*>(&At_h[k][tr8 + 4]);
            const float4 wl = *reinterpret_cast<const float4*>(&Ws_l[k][tc4]);
            const float4 wr = *reinterpret_cast<const float4*>(&Ws_r[k][tc4]);
            const float a_[8] = {aa0.x, aa0.y, aa0.z, aa0.w, aa1.x, aa1.y, aa1.z, aa1.w};
            const float h_[8] = {ah0.x, ah0.y, ah0.z, ah0.w, ah1.x, ah1.y, ah1.z, ah1.w};
            const float wls[4] = {wl.x, wl.y, wl.z, wl.w};
            const float wrs[4] = {wr.x, wr.y, wr.z, wr.w};
            #pragma unroll
            for (int r = 0; r < 8; ++r)
                #pragma unroll
                for (int c = 0; c < 4; ++c)
                    acc[r][c] += a_[r] * wls[c] + h_[r] * wrs[c];
        }
        __syncthreads();
    }

    const float4 ga = *reinterpret_cast<const float4*>(&gamma[tc4]);
    const float4 be = *reinterpret_cast<const float4*>(&beta[tc4]);
    const float4 rm = *reinterpret_cast<const float4*>(&rmean[tc4]);
    const float4 rv = *reinterpret_cast<const float4*>(&rvar[tc4]);
    const float4 bb = *reinterpret_cast<const float4*>(&bl[tc4]);
    float sc[4], sh[4];
    sc[0] = ga.x * rsqrtf(rv.x + EPSBN); sh[0] = (bb.x - rm.x) * sc[0] + be.x;
    sc[1] = ga.y * rsqrtf(rv.y + EPSBN); sh[1] = (bb.y - rm.y) * sc[1] + be.y;
    sc[2] = ga.z * rsqrtf(rv.z + EPSBN); sh[2] = (bb.z - rm.z) * sc[2] + be.z;
    sc[3] = ga.w * rsqrtf(rv.w + EPSBN); sh[3] = (bb.w - rm.w) * sc[3] + be.w;
    #pragma unroll
    for (int r = 0; r < 8; ++r) {
        int grow = row0 + tr8 + r;
        if (grow < nrows) {
            float4 o;
            o.x = fmaxf(acc[r][0] * sc[0] + sh[0], 0.f);
            o.y = fmaxf(acc[r][1] * sc[1] + sh[1], 0.f);
            o.z = fmaxf(acc[r][2] * sc[2] + sh[2], 0.f);
            o.w = fmaxf(acc[r][3] * sc[3] + sh[3], 0.f);
            *reinterpret_cast<float4*>(&hout[grow * D + tc4]) = o;
        }
    }
}

// ---------------------------------------------------------------- fused pool + MLP head
// one block (128 threads) per graph: mean-pool into LDS, MLP1 (128), MLP2 (64)
__global__ __launch_bounds__(128) void k_head(const float* __restrict__ h,
                                              const int* __restrict__ bidx,
                                              const float* __restrict__ W1,
                                              const float* __restrict__ b1,
                                              const float* __restrict__ W2,
                                              const float* __restrict__ b2,
                                              float* __restrict__ out) {
    __shared__ float gs[D];
    __shared__ float g1s[D];
    const int gid = blockIdx.x;
    const int t = threadIdx.x;
    int lo = 0, hi = NNODES;
    while (lo < hi) { int m = (lo + hi) >> 1; if (bidx[m] < gid) lo = m + 1; else hi = m; }
    const int s = lo;
    lo = s; hi = NNODES;
    while (lo < hi) { int m = (lo + hi) >> 1; if (bidx[m] < gid + 1) lo = m + 1; else hi = m; }
    const int e = lo;
    float acc = 0.f;
    int i = s;
    for (; i + 4 <= e; i += 4) {
        acc += h[(i + 0) * D + t] + h[(i + 1) * D + t]
             + h[(i + 2) * D + t] + h[(i + 3) * D + t];
    }
    for (; i < e; ++i) acc += h[i * D + t];
    const int c = e - s;
    gs[t] = acc / (float)(c > 0 ? c : 1);
    __syncthreads();
    float a1 = b1[t];
    #pragma unroll 8
    for (int k = 0; k < D; ++k) a1 += gs[k] * W1[k * D + t];
    g1s[t] = fmaxf(a1, 0.f);
    __syncthreads();
    if (t < NOUT) {
        float a2 = b2[t];
        #pragma unroll 8
        for (int k = 0; k < D; ++k) a2 += g1s[k] * W2[k * NOUT + t];
        out[gid * NOUT + t] = a2;
    }
}

// ---------------------------------------------------------------- launch
extern "C" void kernel_launch(void* const* d_in, const int* in_sizes, int n_in,
                              void* d_out, int out_size, void* d_ws, size_t ws_size,
                              hipStream_t stream) {
    const float* x     = (const float*)d_in[0];
    const int*   ei    = (const int*)d_in[1];
    const int*   b     = (const int*)d_in[2];
    const float* Wl    = (const float*)d_in[3];
    const float* bl    = (const float*)d_in[4];
    const float* Wr    = (const float*)d_in[5];
    const float* gamma = (const float*)d_in[6];
    const float* beta  = (const float*)d_in[7];
    const float* rmean = (const float*)d_in[8];
    const float* rvar  = (const float*)d_in[9];
    const float* W1    = (const float*)d_in[10];
    const float* b1    = (const float*)d_in[11];
    const float* W2    = (const float*)d_in[12];
    const float* b2    = (const float*)d_in[13];
    float* out = (float*)d_out;

    char* p = (char*)d_ws;
    auto take = [&](size_t bytes) { char* r = p; p += (bytes + 255) & ~size_t(255); return r; };
    float* h1   = (float*)take(sizeof(float) * NNODES * D);
    float* h2   = (float*)take(sizeof(float) * NNODES * D);
    float* agg  = (float*)take(sizeof(float) * NNODES * D);
    int* esrc   = (int*)take(sizeof(int) * NEDGES);
    int* offs   = (int*)take(sizeof(int) * (NNODES + 1));
    int* cursor = (int*)take(sizeof(int) * NNODES);
    int* deg    = (int*)take(sizeof(int) * NNODES);

    const int NB_N = (NNODES + 255) / 256;    // 196
    const int NB_E = (NEDGES + 255) / 256;    // 3125

    // CSR build (4 launches)
    k_zero_i32<<<NB_N, 256, 0, stream>>>(deg, NNODES);
    k_count<<<NB_E, 256, 0, stream>>>(ei, deg);
    k_scan_all<<<1, 1024, 0, stream>>>(deg, offs, cursor);
    k_fill<<<NB_E, 256, 0, stream>>>(ei, cursor, esrc);

    const int GB = (NNODES + 63) / 64;        // 782
    const float* hin = x;
    float* bufs[2] = {h1, h2};
    for (int l = 0; l < 3; ++l) {
        float* hout = bufs[l & 1];
        k_aggregate<<<(NNODES + 3) / 4, 256, 0, stream>>>(hin, offs, esrc, agg);
        k_sage_gemm<<<GB, 256, 0, stream>>>(agg, hin,
                                            Wl + (size_t)l * D * D, Wr + (size_t)l * D * D,
                                            bl + l * D, gamma + l * D, beta + l * D,
                                            rmean + l * D, rvar + l * D, hout, NNODES);
        hin = hout;
    }

    k_head<<<NGRAPH, 128, 0, stream>>>(hin, b, W1, b1, W2, b2, out);
}

// Round 4
// 634.865 us; speedup vs baseline: 1.3217x; 1.3217x over previous
//
#include <hip/hip_runtime.h>

#define D 128
#define NNODES 50000
#define NEDGES 800000
#define NGRAPH 512
#define NOUT 64
#define EPSBN 1e-5f

// ---------------------------------------------------------------- utilities
__global__ __launch_bounds__(256) void k_zero_i32(int* __restrict__ p, int n) {
    int i = blockIdx.x * 256 + threadIdx.x;
    if (i < n) p[i] = 0;
}

// ---------------------------------------------------------------- CSR build
__global__ __launch_bounds__(256) void k_count(const int* __restrict__ ei, int* __restrict__ deg) {
    int e = blockIdx.x * 256 + threadIdx.x;
    if (e < NEDGES) atomicAdd(&deg[ei[NEDGES + e]], 1);  // dst = ei[1][e]
}

// single-block scan over all NNODES degrees -> offsets (incl+1) and cursor (excl)
__global__ __launch_bounds__(1024) void k_scan_all(const int* __restrict__ deg,
                                                   int* __restrict__ offs,
                                                   int* __restrict__ cursor) {
    __shared__ int s[1024];
    const int T = 1024;
    const int C = (NNODES + T - 1) / T;  // 49
    const int t = threadIdx.x;
    const int beg = t * C;
    const int end = (beg + C < NNODES) ? beg + C : NNODES;
    int sum = 0;
    for (int i = beg; i < end; ++i) sum += deg[i];
    s[t] = sum;
    __syncthreads();
    #pragma unroll
    for (int off = 1; off < T; off <<= 1) {
        int v = (t >= off) ? s[t - off] : 0;
        __syncthreads();
        s[t] += v;
        __syncthreads();
    }
    int run = s[t] - sum;  // exclusive prefix of this thread's chunk
    for (int i = beg; i < end; ++i) {
        int d = deg[i];
        cursor[i] = run;
        offs[i + 1] = run + d;
        run += d;
    }
    if (t == 0) offs[0] = 0;
}

__global__ __launch_bounds__(256) void k_fill(const int* __restrict__ ei, int* __restrict__ cursor,
                                              int* __restrict__ esrc) {
    int e = blockIdx.x * 256 + threadIdx.x;
    if (e < NEDGES) {
        int dst = ei[NEDGES + e];
        int pos = atomicAdd(&cursor[dst], 1);
        esrc[pos] = ei[e];  // src = ei[0][e]
    }
}

// ---------------------------------------------------------------- mean aggregation (gather)
// one HALF-WAVE (32 lanes, float4 each = full 512B row) per node; 4-edge unroll
// -> 8 gather rows in flight per wave
__global__ __launch_bounds__(256) void k_aggregate(const float* __restrict__ hin,
                                                   const int* __restrict__ offs,
                                                   const int* __restrict__ esrc,
                                                   float* __restrict__ agg) {
    const int hw = threadIdx.x >> 5;         // half-wave 0..7
    const int lane = threadIdx.x & 31;
    const int node = blockIdx.x * 8 + hw;
    if (node >= NNODES) return;
    const int beg = offs[node];
    const int end = offs[node + 1];
    const int c4 = lane * 4;
    float4 a0 = {0.f, 0.f, 0.f, 0.f};
    float4 a1 = {0.f, 0.f, 0.f, 0.f};
    float4 a2 = {0.f, 0.f, 0.f, 0.f};
    float4 a3 = {0.f, 0.f, 0.f, 0.f};
    int e = beg;
    for (; e + 4 <= end; e += 4) {
        int s0 = esrc[e + 0], s1 = esrc[e + 1], s2 = esrc[e + 2], s3 = esrc[e + 3];
        float4 v0 = *reinterpret_cast<const float4*>(&hin[s0 * D + c4]);
        float4 v1 = *reinterpret_cast<const float4*>(&hin[s1 * D + c4]);
        float4 v2 = *reinterpret_cast<const float4*>(&hin[s2 * D + c4]);
        float4 v3 = *reinterpret_cast<const float4*>(&hin[s3 * D + c4]);
        a0.x += v0.x; a0.y += v0.y; a0.z += v0.z; a0.w += v0.w;
        a1.x += v1.x; a1.y += v1.y; a1.z += v1.z; a1.w += v1.w;
        a2.x += v2.x; a2.y += v2.y; a2.z += v2.z; a2.w += v2.w;
        a3.x += v3.x; a3.y += v3.y; a3.z += v3.z; a3.w += v3.w;
    }
    for (; e < end; ++e) {
        int s0 = esrc[e];
        float4 v0 = *reinterpret_cast<const float4*>(&hin[s0 * D + c4]);
        a0.x += v0.x; a0.y += v0.y; a0.z += v0.z; a0.w += v0.w;
    }
    a0.x += a1.x + a2.x + a3.x;
    a0.y += a1.y + a2.y + a3.y;
    a0.z += a1.z + a2.z + a3.z;
    a0.w += a1.w + a2.w + a3.w;
    const int dg = end - beg;
    const float inv = 1.f / (float)(dg > 0 ? dg : 1);
    float4 o; o.x = a0.x * inv; o.y = a0.y * inv; o.z = a0.z * inv; o.w = a0.w * inv;
    *reinterpret_cast<float4*>(&agg[node * D + c4]) = o;
}

// ---------------------------------------------------------------- fused dual-GEMM + BN + ReLU
// View as single GEMM: C = [agg|hin] @ [Wl;Wr], K=256, per-chunk source swap.
// Tile 128x128, 256 threads, 8x8 microtile, BK=32.
// LDS 33792B -> 4 blocks/CU; launch_bounds(256,4) caps VGPR at 128.
__global__ __launch_bounds__(256, 4) void k_sage_gemm(const float* __restrict__ agg,
                                                      const float* __restrict__ hin,
                                                      const float* __restrict__ Wl,
                                                      const float* __restrict__ Wr,
                                                      const float* __restrict__ bl,
                                                      const float* __restrict__ gamma,
                                                      const float* __restrict__ beta,
                                                      const float* __restrict__ rmean,
                                                      const float* __restrict__ rvar,
                                                      float* __restrict__ hout, int nrows) {
    __shared__ float At[32][132];   // [k][row] transposed A chunk; stride 132 (16B-aligned, bank-spread)
    __shared__ float Ws[32][132];   // [k][col] W chunk

    const int tid = threadIdx.x;
    const int trow = tid >> 4;      // 0..15
    const int tcol = tid & 15;      // 0..15
    const int r0 = trow * 8;
    const int c0 = tcol * 8;
    const int row0 = blockIdx.x * 128;

    float acc[8][8];
    #pragma unroll
    for (int r = 0; r < 8; ++r)
        #pragma unroll
        for (int c = 0; c < 8; ++c) acc[r][c] = 0.f;

    for (int kc = 0; kc < 8; ++kc) {
        const float* __restrict__ Asrc = (kc < 4) ? agg : hin;
        const float* __restrict__ Wsrc = (kc < 4) ? Wl : Wr;
        const int koff = (kc & 3) * 32;

        // stage A transposed: 128 rows x 32 k; 4 float4 loads/thread, 16 b32 stores
        #pragma unroll
        for (int t = 0; t < 4; ++t) {
            int l = tid + t * 256;          // 0..1023
            int ar = l >> 3;                // row 0..127
            int kq = l & 7;                 // k-quad 0..7
            int grow = row0 + ar;
            if (grow >= nrows) grow = nrows - 1;
            const float4 v = *reinterpret_cast<const float4*>(&Asrc[grow * D + koff + kq * 4]);
            At[kq * 4 + 0][ar] = v.x;
            At[kq * 4 + 1][ar] = v.y;
            At[kq * 4 + 2][ar] = v.z;
            At[kq * 4 + 3][ar] = v.w;
        }
        // stage W: 32 k x 128 col; 4 float4 per thread (b128 stores)
        #pragma unroll
        for (int t = 0; t < 4; ++t) {
            int l = tid + t * 256;          // 0..1023
            int wk = l >> 5;                // 0..31
            int wc = (l & 31) * 4;          // 0..124
            *reinterpret_cast<float4*>(&Ws[wk][wc]) =
                *reinterpret_cast<const float4*>(&Wsrc[(koff + wk) * D + wc]);
        }
        __syncthreads();

        #pragma unroll 4
        for (int k = 0; k < 32; ++k) {
            const float4 a0 = *reinterpret_cast<const float4*>(&At[k][r0]);
            const float4 a1 = *reinterpret_cast<const float4*>(&At[k][r0 + 4]);
            const float4 w0 = *reinterpret_cast<const float4*>(&Ws[k][c0]);
            const float4 w1 = *reinterpret_cast<const float4*>(&Ws[k][c0 + 4]);
            const float a_[8] = {a0.x, a0.y, a0.z, a0.w, a1.x, a1.y, a1.z, a1.w};
            const float w_[8] = {w0.x, w0.y, w0.z, w0.w, w1.x, w1.y, w1.z, w1.w};
            #pragma unroll
            for (int r = 0; r < 8; ++r)
                #pragma unroll
                for (int c = 0; c < 8; ++c)
                    acc[r][c] += a_[r] * w_[c];
        }
        __syncthreads();
    }

    // epilogue: + bl, BN(eval), ReLU over cols c0..c0+7
    float sc[8], sh[8];
    #pragma unroll
    for (int j = 0; j < 8; ++j) {
        const int c = c0 + j;
        const float s = gamma[c] * rsqrtf(rvar[c] + EPSBN);
        sc[j] = s;
        sh[j] = (bl[c] - rmean[c]) * s + beta[c];
    }
    #pragma unroll
    for (int r = 0; r < 8; ++r) {
        const int grow = row0 + r0 + r;
        if (grow < nrows) {
            float4 o0, o1;
            o0.x = fmaxf(acc[r][0] * sc[0] + sh[0], 0.f);
            o0.y = fmaxf(acc[r][1] * sc[1] + sh[1], 0.f);
            o0.z = fmaxf(acc[r][2] * sc[2] + sh[2], 0.f);
            o0.w = fmaxf(acc[r][3] * sc[3] + sh[3], 0.f);
            o1.x = fmaxf(acc[r][4] * sc[4] + sh[4], 0.f);
            o1.y = fmaxf(acc[r][5] * sc[5] + sh[5], 0.f);
            o1.z = fmaxf(acc[r][6] * sc[6] + sh[6], 0.f);
            o1.w = fmaxf(acc[r][7] * sc[7] + sh[7], 0.f);
            *reinterpret_cast<float4*>(&hout[grow * D + c0]) = o0;
            *reinterpret_cast<float4*>(&hout[grow * D + c0 + 4]) = o1;
        }
    }
}

// ---------------------------------------------------------------- fused pool + MLP head
__global__ __launch_bounds__(128) void k_head(const float* __restrict__ h,
                                              const int* __restrict__ bidx,
                                              const float* __restrict__ W1,
                                              const float* __restrict__ b1,
                                              const float* __restrict__ W2,
                                              const float* __restrict__ b2,
                                              float* __restrict__ out) {
    __shared__ float gs[D];
    __shared__ float g1s[D];
    const int gid = blockIdx.x;
    const int t = threadIdx.x;
    int lo = 0, hi = NNODES;
    while (lo < hi) { int m = (lo + hi) >> 1; if (bidx[m] < gid) lo = m + 1; else hi = m; }
    const int s = lo;
    lo = s; hi = NNODES;
    while (lo < hi) { int m = (lo + hi) >> 1; if (bidx[m] < gid + 1) lo = m + 1; else hi = m; }
    const int e = lo;
    float acc = 0.f;
    int i = s;
    for (; i + 4 <= e; i += 4) {
        acc += h[(i + 0) * D + t] + h[(i + 1) * D + t]
             + h[(i + 2) * D + t] + h[(i + 3) * D + t];
    }
    for (; i < e; ++i) acc += h[i * D + t];
    const int c = e - s;
    gs[t] = acc / (float)(c > 0 ? c : 1);
    __syncthreads();
    float a1 = b1[t];
    #pragma unroll 8
    for (int k = 0; k < D; ++k) a1 += gs[k] * W1[k * D + t];
    g1s[t] = fmaxf(a1, 0.f);
    __syncthreads();
    if (t < NOUT) {
        float a2 = b2[t];
        #pragma unroll 8
        for (int k = 0; k < D; ++k) a2 += g1s[k] * W2[k * NOUT + t];
        out[gid * NOUT + t] = a2;
    }
}

// ---------------------------------------------------------------- launch
extern "C" void kernel_launch(void* const* d_in, const int* in_sizes, int n_in,
                              void* d_out, int out_size, void* d_ws, size_t ws_size,
                              hipStream_t stream) {
    const float* x     = (const float*)d_in[0];
    const int*   ei    = (const int*)d_in[1];
    const int*   b     = (const int*)d_in[2];
    const float* Wl    = (const float*)d_in[3];
    const float* bl    = (const float*)d_in[4];
    const float* Wr    = (const float*)d_in[5];
    const float* gamma = (const float*)d_in[6];
    const float* beta  = (const float*)d_in[7];
    const float* rmean = (const float*)d_in[8];
    const float* rvar  = (const float*)d_in[9];
    const float* W1    = (const float*)d_in[10];
    const float* b1    = (const float*)d_in[11];
    const float* W2    = (const float*)d_in[12];
    const float* b2    = (const float*)d_in[13];
    float* out = (float*)d_out;

    char* p = (char*)d_ws;
    auto take = [&](size_t bytes) { char* r = p; p += (bytes + 255) & ~size_t(255); return r; };
    float* h1   = (float*)take(sizeof(float) * NNODES * D);
    float* h2   = (float*)take(sizeof(float) * NNODES * D);
    float* agg  = (float*)take(sizeof(float) * NNODES * D);
    int* esrc   = (int*)take(sizeof(int) * NEDGES);
    int* offs   = (int*)take(sizeof(int) * (NNODES + 1));
    int* cursor = (int*)take(sizeof(int) * NNODES);
    int* deg    = (int*)take(sizeof(int) * NNODES);

    const int NB_N = (NNODES + 255) / 256;    // 196
    const int NB_E = (NEDGES + 255) / 256;    // 3125

    // CSR build (4 launches)
    k_zero_i32<<<NB_N, 256, 0, stream>>>(deg, NNODES);
    k_count<<<NB_E, 256, 0, stream>>>(ei, deg);
    k_scan_all<<<1, 1024, 0, stream>>>(deg, offs, cursor);
    k_fill<<<NB_E, 256, 0, stream>>>(ei, cursor, esrc);

    const int GB = (NNODES + 127) / 128;      // 391
    const float* hin = x;
    float* bufs[2] = {h1, h2};
    for (int l = 0; l < 3; ++l) {
        float* hout = bufs[l & 1];
        k_aggregate<<<(NNODES + 7) / 8, 256, 0, stream>>>(hin, offs, esrc, agg);
        k_sage_gemm<<<GB, 256, 0, stream>>>(agg, hin,
                                            Wl + (size_t)l * D * D, Wr + (size_t)l * D * D,
                                            bl + l * D, gamma + l * D, beta + l * D,
                                            rmean + l * D, rvar + l * D, hout, NNODES);
        hin = hout;
    }

    k_head<<<NGRAPH, 128, 0, stream>>>(hin, b, W1, b1, W2, b2, out);
}

// Round 5
// 507.321 us; speedup vs baseline: 1.6540x; 1.2514x over previous
//
#include <hip/hip_runtime.h>

#define D 128
#define NNODES 50000
#define NEDGES 800000
#define NGRAPH 512
#define NOUT 64
#define EPSBN 1e-5f

typedef __attribute__((ext_vector_type(8))) short short8;
typedef __attribute__((ext_vector_type(4))) short short4v;
typedef __attribute__((ext_vector_type(4))) float f32x4;

__device__ inline unsigned short f2bf_rne(float x) {
    unsigned u = __float_as_uint(x);
    unsigned r = (u + 0x7FFFu + ((u >> 16) & 1u)) >> 16;
    return (unsigned short)r;
}
__device__ inline float bf2f(unsigned short h) { return __uint_as_float(((unsigned)h) << 16); }

// ---------------------------------------------------------------- utilities
__global__ __launch_bounds__(256) void k_zero_i32(int* __restrict__ p, int n) {
    int i = blockIdx.x * 256 + threadIdx.x;
    if (i < n) p[i] = 0;
}

// ---------------------------------------------------------------- CSR build
__global__ __launch_bounds__(256) void k_count(const int* __restrict__ ei, int* __restrict__ deg) {
    int e = blockIdx.x * 256 + threadIdx.x;
    if (e < NEDGES) atomicAdd(&deg[ei[NEDGES + e]], 1);  // dst = ei[1][e]
}

// hierarchical scan: block-inclusive partials + per-block sums
__global__ __launch_bounds__(256) void k_scan1(const int* __restrict__ deg, int* __restrict__ incl,
                                               int* __restrict__ bsum, int n) {
    __shared__ int s[256];
    int i = blockIdx.x * 256 + threadIdx.x;
    int v = (i < n) ? deg[i] : 0;
    s[threadIdx.x] = v;
    __syncthreads();
    #pragma unroll
    for (int off = 1; off < 256; off <<= 1) {
        int t = (threadIdx.x >= off) ? s[threadIdx.x - off] : 0;
        __syncthreads();
        s[threadIdx.x] += t;
        __syncthreads();
    }
    if (i < n) incl[i] = s[threadIdx.x];
    if (threadIdx.x == 255) bsum[blockIdx.x] = s[255];
}

__global__ __launch_bounds__(256) void k_scan2(const int* __restrict__ bsum, int* __restrict__ boff, int nb) {
    __shared__ int s[256];
    int v = (threadIdx.x < nb) ? bsum[threadIdx.x] : 0;
    s[threadIdx.x] = v;
    __syncthreads();
    #pragma unroll
    for (int off = 1; off < 256; off <<= 1) {
        int t = (threadIdx.x >= off) ? s[threadIdx.x - off] : 0;
        __syncthreads();
        s[threadIdx.x] += t;
        __syncthreads();
    }
    if (threadIdx.x < nb) boff[threadIdx.x] = s[threadIdx.x] - v;  // exclusive
}

__global__ __launch_bounds__(256) void k_scan3(const int* __restrict__ incl, const int* __restrict__ boff,
                                               const int* __restrict__ deg,
                                               int* __restrict__ offs, int* __restrict__ cursor, int n) {
    int i = blockIdx.x * 256 + threadIdx.x;
    if (i < n) {
        int inc = incl[i] + boff[blockIdx.x];
        offs[i + 1] = inc;
        cursor[i] = inc - deg[i];
    }
    if (i == 0) offs[0] = 0;
}

__global__ __launch_bounds__(256) void k_fill(const int* __restrict__ ei, int* __restrict__ cursor,
                                              int* __restrict__ esrc) {
    int e = blockIdx.x * 256 + threadIdx.x;
    if (e < NEDGES) {
        int dst = ei[NEDGES + e];
        int pos = atomicAdd(&cursor[dst], 1);
        esrc[pos] = ei[e];  // src = ei[0][e]
    }
}

// ---------------------------------------------------------------- mean aggregation (gather)
// one half-wave (32 lanes x float4 = full 512B row) per node; 8-edge unroll
__global__ __launch_bounds__(256) void k_aggregate(const float* __restrict__ hin,
                                                   const int* __restrict__ offs,
                                                   const int* __restrict__ esrc,
                                                   float* __restrict__ agg) {
    const int hw = threadIdx.x >> 5;
    const int lane = threadIdx.x & 31;
    const int node = blockIdx.x * 8 + hw;
    if (node >= NNODES) return;
    const int beg = offs[node];
    const int end = offs[node + 1];
    const int c4 = lane * 4;
    float4 a0 = {0.f, 0.f, 0.f, 0.f};
    float4 a1 = {0.f, 0.f, 0.f, 0.f};
    float4 a2 = {0.f, 0.f, 0.f, 0.f};
    float4 a3 = {0.f, 0.f, 0.f, 0.f};
    int e = beg;
    for (; e + 8 <= end; e += 8) {
        int s0 = esrc[e + 0], s1 = esrc[e + 1], s2 = esrc[e + 2], s3 = esrc[e + 3];
        int s4 = esrc[e + 4], s5 = esrc[e + 5], s6 = esrc[e + 6], s7 = esrc[e + 7];
        float4 v0 = *reinterpret_cast<const float4*>(&hin[s0 * D + c4]);
        float4 v1 = *reinterpret_cast<const float4*>(&hin[s1 * D + c4]);
        float4 v2 = *reinterpret_cast<const float4*>(&hin[s2 * D + c4]);
        float4 v3 = *reinterpret_cast<const float4*>(&hin[s3 * D + c4]);
        float4 v4 = *reinterpret_cast<const float4*>(&hin[s4 * D + c4]);
        float4 v5 = *reinterpret_cast<const float4*>(&hin[s5 * D + c4]);
        float4 v6 = *reinterpret_cast<const float4*>(&hin[s6 * D + c4]);
        float4 v7 = *reinterpret_cast<const float4*>(&hin[s7 * D + c4]);
        a0.x += v0.x + v4.x; a0.y += v0.y + v4.y; a0.z += v0.z + v4.z; a0.w += v0.w + v4.w;
        a1.x += v1.x + v5.x; a1.y += v1.y + v5.y; a1.z += v1.z + v5.z; a1.w += v1.w + v5.w;
        a2.x += v2.x + v6.x; a2.y += v2.y + v6.y; a2.z += v2.z + v6.z; a2.w += v2.w + v6.w;
        a3.x += v3.x + v7.x; a3.y += v3.y + v7.y; a3.z += v3.z + v7.z; a3.w += v3.w + v7.w;
    }
    for (; e + 4 <= end; e += 4) {
        int s0 = esrc[e + 0], s1 = esrc[e + 1], s2 = esrc[e + 2], s3 = esrc[e + 3];
        float4 v0 = *reinterpret_cast<const float4*>(&hin[s0 * D + c4]);
        float4 v1 = *reinterpret_cast<const float4*>(&hin[s1 * D + c4]);
        float4 v2 = *reinterpret_cast<const float4*>(&hin[s2 * D + c4]);
        float4 v3 = *reinterpret_cast<const float4*>(&hin[s3 * D + c4]);
        a0.x += v0.x; a0.y += v0.y; a0.z += v0.z; a0.w += v0.w;
        a1.x += v1.x; a1.y += v1.y; a1.z += v1.z; a1.w += v1.w;
        a2.x += v2.x; a2.y += v2.y; a2.z += v2.z; a2.w += v2.w;
        a3.x += v3.x; a3.y += v3.y; a3.z += v3.z; a3.w += v3.w;
    }
    for (; e < end; ++e) {
        int s0 = esrc[e];
        float4 v0 = *reinterpret_cast<const float4*>(&hin[s0 * D + c4]);
        a0.x += v0.x; a0.y += v0.y; a0.z += v0.z; a0.w += v0.w;
    }
    a0.x += a1.x + a2.x + a3.x;
    a0.y += a1.y + a2.y + a3.y;
    a0.z += a1.z + a2.z + a3.z;
    a0.w += a1.w + a2.w + a3.w;
    const int dg = end - beg;
    const float inv = 1.f / (float)(dg > 0 ? dg : 1);
    float4 o; o.x = a0.x * inv; o.y = a0.y * inv; o.z = a0.z * inv; o.w = a0.w * inv;
    *reinterpret_cast<float4*>(&agg[node * D + c4]) = o;
}

// ---------------------------------------------------------------- fused dual-GEMM + BN + ReLU (MFMA)
// C = [agg|hin] @ [Wl;Wr] as K=256 with per-chunk source swap; split-bf16 (hi+lo, 4 terms)
// block: 256 threads = 4 waves in 2x2; wave computes 64x64 via 4x4 tiles of 16x16x32 MFMA
__global__ __launch_bounds__(256) void k_sage_gemm(const float* __restrict__ agg,
                                                   const float* __restrict__ hin,
                                                   const float* __restrict__ Wl,
                                                   const float* __restrict__ Wr,
                                                   const float* __restrict__ bl,
                                                   const float* __restrict__ gamma,
                                                   const float* __restrict__ beta,
                                                   const float* __restrict__ rmean,
                                                   const float* __restrict__ rvar,
                                                   float* __restrict__ hout, int nrows) {
    __shared__ unsigned short Ah[128][40];  // [row][k] bf16 hi; stride 40 -> 2-way max conflicts
    __shared__ unsigned short Al[128][40];
    __shared__ unsigned short Bh[128][40];  // W transposed: [col][k]
    __shared__ unsigned short Bl[128][40];

    const int tid = threadIdx.x;
    const int wave = tid >> 6;
    const int lane = tid & 63;
    const int wr = wave >> 1, wc = wave & 1;
    const int l15 = lane & 15, l4 = lane >> 4;
    const int row0 = blockIdx.x * 128;

    f32x4 acc[4][4];
    #pragma unroll
    for (int mi = 0; mi < 4; ++mi)
        #pragma unroll
        for (int ni = 0; ni < 4; ++ni)
            acc[mi][ni] = (f32x4){0.f, 0.f, 0.f, 0.f};

    for (int kc = 0; kc < 8; ++kc) {
        const float* __restrict__ Asrc = (kc < 4) ? agg : hin;
        const float* __restrict__ Wsrc = (kc < 4) ? Wl : Wr;
        const int koff = (kc & 3) * 32;

        // stage A rows (no transpose): 128 rows x 32 k
        #pragma unroll
        for (int i = 0; i < 4; ++i) {
            int l = tid + i * 256;         // 0..1023
            int ar = l >> 3;               // row 0..127
            int kq = l & 7;                // k-quad
            int grow = row0 + ar;
            if (grow >= nrows) grow = nrows - 1;
            float4 v = *reinterpret_cast<const float4*>(&Asrc[grow * D + koff + kq * 4]);
            unsigned short h0 = f2bf_rne(v.x), h1 = f2bf_rne(v.y), h2 = f2bf_rne(v.z), h3 = f2bf_rne(v.w);
            unsigned short q0 = f2bf_rne(v.x - bf2f(h0)), q1 = f2bf_rne(v.y - bf2f(h1));
            unsigned short q2 = f2bf_rne(v.z - bf2f(h2)), q3 = f2bf_rne(v.w - bf2f(h3));
            short4v hs = {(short)h0, (short)h1, (short)h2, (short)h3};
            short4v qs = {(short)q0, (short)q1, (short)q2, (short)q3};
            *reinterpret_cast<short4v*>(&Ah[ar][kq * 4]) = hs;
            *reinterpret_cast<short4v*>(&Al[ar][kq * 4]) = qs;
        }
        // stage W transposed: Bt[col][k]
        #pragma unroll
        for (int i = 0; i < 4; ++i) {
            int l = tid + i * 256;         // 0..1023
            int wk = l >> 5;               // 0..31
            int wc4 = (l & 31) * 4;        // col base
            float4 v = *reinterpret_cast<const float4*>(&Wsrc[(koff + wk) * D + wc4]);
            unsigned short h0 = f2bf_rne(v.x), h1 = f2bf_rne(v.y), h2 = f2bf_rne(v.z), h3 = f2bf_rne(v.w);
            Bh[wc4 + 0][wk] = h0; Bl[wc4 + 0][wk] = f2bf_rne(v.x - bf2f(h0));
            Bh[wc4 + 1][wk] = h1; Bl[wc4 + 1][wk] = f2bf_rne(v.y - bf2f(h1));
            Bh[wc4 + 2][wk] = h2; Bl[wc4 + 2][wk] = f2bf_rne(v.z - bf2f(h2));
            Bh[wc4 + 3][wk] = h3; Bl[wc4 + 3][wk] = f2bf_rne(v.w - bf2f(h3));
        }
        __syncthreads();

        short8 bhf[4], blf[4];
        #pragma unroll
        for (int ni = 0; ni < 4; ++ni) {
            int c = wc * 64 + ni * 16 + l15;
            bhf[ni] = *reinterpret_cast<const short8*>(&Bh[c][l4 * 8]);
            blf[ni] = *reinterpret_cast<const short8*>(&Bl[c][l4 * 8]);
        }
        #pragma unroll
        for (int mi = 0; mi < 4; ++mi) {
            int r = wr * 64 + mi * 16 + l15;
            short8 ahf = *reinterpret_cast<const short8*>(&Ah[r][l4 * 8]);
            short8 alf = *reinterpret_cast<const short8*>(&Al[r][l4 * 8]);
            #pragma unroll
            for (int ni = 0; ni < 4; ++ni) {
                acc[mi][ni] = __builtin_amdgcn_mfma_f32_16x16x32_bf16(ahf, bhf[ni], acc[mi][ni], 0, 0, 0);
                acc[mi][ni] = __builtin_amdgcn_mfma_f32_16x16x32_bf16(ahf, blf[ni], acc[mi][ni], 0, 0, 0);
                acc[mi][ni] = __builtin_amdgcn_mfma_f32_16x16x32_bf16(alf, bhf[ni], acc[mi][ni], 0, 0, 0);
                acc[mi][ni] = __builtin_amdgcn_mfma_f32_16x16x32_bf16(alf, blf[ni], acc[mi][ni], 0, 0, 0);
            }
        }
        __syncthreads();
    }

    // epilogue: + bl, BN(eval), ReLU.  C/D map: col = lane&15, row = (lane>>4)*4 + j
    float scn[4], shn[4];
    #pragma unroll
    for (int ni = 0; ni < 4; ++ni) {
        int c = wc * 64 + ni * 16 + l15;
        float s = gamma[c] * rsqrtf(rvar[c] + EPSBN);
        scn[ni] = s;
        shn[ni] = (bl[c] - rmean[c]) * s + beta[c];
    }
    #pragma unroll
    for (int mi = 0; mi < 4; ++mi) {
        #pragma unroll
        for (int ni = 0; ni < 4; ++ni) {
            int c = wc * 64 + ni * 16 + l15;
            #pragma unroll
            for (int j = 0; j < 4; ++j) {
                int grow = row0 + wr * 64 + mi * 16 + l4 * 4 + j;
                if (grow < nrows)
                    hout[grow * D + c] = fmaxf(acc[mi][ni][j] * scn[ni] + shn[ni], 0.f);
            }
        }
    }
}

// ---------------------------------------------------------------- fused pool + MLP head
__global__ __launch_bounds__(128) void k_head(const float* __restrict__ h,
                                              const int* __restrict__ bidx,
                                              const float* __restrict__ W1,
                                              const float* __restrict__ b1,
                                              const float* __restrict__ W2,
                                              const float* __restrict__ b2,
                                              float* __restrict__ out) {
    __shared__ float gs[D];
    __shared__ float g1s[D];
    const int gid = blockIdx.x;
    const int t = threadIdx.x;
    int lo = 0, hi = NNODES;
    while (lo < hi) { int m = (lo + hi) >> 1; if (bidx[m] < gid) lo = m + 1; else hi = m; }
    const int s = lo;
    lo = s; hi = NNODES;
    while (lo < hi) { int m = (lo + hi) >> 1; if (bidx[m] < gid + 1) lo = m + 1; else hi = m; }
    const int e = lo;
    float acc = 0.f;
    int i = s;
    for (; i + 4 <= e; i += 4) {
        acc += h[(i + 0) * D + t] + h[(i + 1) * D + t]
             + h[(i + 2) * D + t] + h[(i + 3) * D + t];
    }
    for (; i < e; ++i) acc += h[i * D + t];
    const int c = e - s;
    gs[t] = acc / (float)(c > 0 ? c : 1);
    __syncthreads();
    float a1 = b1[t];
    #pragma unroll 8
    for (int k = 0; k < D; ++k) a1 += gs[k] * W1[k * D + t];
    g1s[t] = fmaxf(a1, 0.f);
    __syncthreads();
    if (t < NOUT) {
        float a2 = b2[t];
        #pragma unroll 8
        for (int k = 0; k < D; ++k) a2 += g1s[k] * W2[k * NOUT + t];
        out[gid * NOUT + t] = a2;
    }
}

// ---------------------------------------------------------------- launch
extern "C" void kernel_launch(void* const* d_in, const int* in_sizes, int n_in,
                              void* d_out, int out_size, void* d_ws, size_t ws_size,
                              hipStream_t stream) {
    const float* x     = (const float*)d_in[0];
    const int*   ei    = (const int*)d_in[1];
    const int*   b     = (const int*)d_in[2];
    const float* Wl    = (const float*)d_in[3];
    const float* bl    = (const float*)d_in[4];
    const float* Wr    = (const float*)d_in[5];
    const float* gamma = (const float*)d_in[6];
    const float* beta  = (const float*)d_in[7];
    const float* rmean = (const float*)d_in[8];
    const float* rvar  = (const float*)d_in[9];
    const float* W1    = (const float*)d_in[10];
    const float* b1    = (const float*)d_in[11];
    const float* W2    = (const float*)d_in[12];
    const float* b2    = (const float*)d_in[13];
    float* out = (float*)d_out;

    char* p = (char*)d_ws;
    auto take = [&](size_t bytes) { char* r = p; p += (bytes + 255) & ~size_t(255); return r; };
    float* h1   = (float*)take(sizeof(float) * NNODES * D);
    float* h2   = (float*)take(sizeof(float) * NNODES * D);
    float* agg  = (float*)take(sizeof(float) * NNODES * D);
    int* esrc   = (int*)take(sizeof(int) * NEDGES);
    int* offs   = (int*)take(sizeof(int) * (NNODES + 1));
    int* cursor = (int*)take(sizeof(int) * NNODES);
    int* deg    = (int*)take(sizeof(int) * NNODES);
    int* incl   = (int*)take(sizeof(int) * NNODES);
    int* bsum   = (int*)take(sizeof(int) * 256);
    int* boff   = (int*)take(sizeof(int) * 256);

    const int NB_N = (NNODES + 255) / 256;    // 196
    const int NB_E = (NEDGES + 255) / 256;    // 3125

    // CSR build (6 small launches; hierarchical scan instead of 110us serial scan)
    k_zero_i32<<<NB_N, 256, 0, stream>>>(deg, NNODES);
    k_count<<<NB_E, 256, 0, stream>>>(ei, deg);
    k_scan1<<<NB_N, 256, 0, stream>>>(deg, incl, bsum, NNODES);
    k_scan2<<<1, 256, 0, stream>>>(bsum, boff, NB_N);
    k_scan3<<<NB_N, 256, 0, stream>>>(incl, boff, deg, offs, cursor, NNODES);
    k_fill<<<NB_E, 256, 0, stream>>>(ei, cursor, esrc);

    const int GB = (NNODES + 127) / 128;      // 391
    const float* hin = x;
    float* bufs[2] = {h1, h2};
    for (int l = 0; l < 3; ++l) {
        float* hout = bufs[l & 1];
        k_aggregate<<<(NNODES + 7) / 8, 256, 0, stream>>>(hin, offs, esrc, agg);
        k_sage_gemm<<<GB, 256, 0, stream>>>(agg, hin,
                                            Wl + (size_t)l * D * D, Wr + (size_t)l * D * D,
                                            bl + l * D, gamma + l * D, beta + l * D,
                                            rmean + l * D, rvar + l * D, hout, NNODES);
        hin = hout;
    }

    k_head<<<NGRAPH, 128, 0, stream>>>(hin, b, W1, b1, W2, b2, out);
}

// Round 6
// 441.614 us; speedup vs baseline: 1.9001x; 1.1488x over previous
//
#include <hip/hip_runtime.h>

#define D 128
#define NNODES 50000
#define NEDGES 800000
#define NGRAPH 512
#define NOUT 64
#define EPSBN 1e-5f

typedef __attribute__((ext_vector_type(8))) short short8;
typedef __attribute__((ext_vector_type(4))) short short4v;
typedef __attribute__((ext_vector_type(4))) float f32x4;

__device__ inline unsigned short f2bf_rne(float x) {
    unsigned u = __float_as_uint(x);
    unsigned r = (u + 0x7FFFu + ((u >> 16) & 1u)) >> 16;
    return (unsigned short)r;
}
__device__ inline float bf2f(unsigned short h) { return __uint_as_float(((unsigned)h) << 16); }

// ---------------------------------------------------------------- utilities
__global__ __launch_bounds__(256) void k_zero_i32(int* __restrict__ p, int n) {
    int i = blockIdx.x * 256 + threadIdx.x;
    if (i < n) p[i] = 0;
}

// x (fp32) -> xb (bf16)
__global__ __launch_bounds__(256) void k_cvt_bf16(const float* __restrict__ x,
                                                  unsigned short* __restrict__ xb, int n4) {
    int i = blockIdx.x * 256 + threadIdx.x;
    if (i < n4) {
        float4 v = *reinterpret_cast<const float4*>(&x[i * 4]);
        ushort4 o;
        o.x = f2bf_rne(v.x); o.y = f2bf_rne(v.y); o.z = f2bf_rne(v.z); o.w = f2bf_rne(v.w);
        *reinterpret_cast<ushort4*>(&xb[i * 4]) = o;
    }
}

// ---------------------------------------------------------------- CSR build
__global__ __launch_bounds__(256) void k_count(const int* __restrict__ ei, int* __restrict__ deg) {
    int e = blockIdx.x * 256 + threadIdx.x;
    if (e < NEDGES) atomicAdd(&deg[ei[NEDGES + e]], 1);  // dst = ei[1][e]
}

__global__ __launch_bounds__(256) void k_scan1(const int* __restrict__ deg, int* __restrict__ incl,
                                               int* __restrict__ bsum, int n) {
    __shared__ int s[256];
    int i = blockIdx.x * 256 + threadIdx.x;
    int v = (i < n) ? deg[i] : 0;
    s[threadIdx.x] = v;
    __syncthreads();
    #pragma unroll
    for (int off = 1; off < 256; off <<= 1) {
        int t = (threadIdx.x >= off) ? s[threadIdx.x - off] : 0;
        __syncthreads();
        s[threadIdx.x] += t;
        __syncthreads();
    }
    if (i < n) incl[i] = s[threadIdx.x];
    if (threadIdx.x == 255) bsum[blockIdx.x] = s[255];
}

__global__ __launch_bounds__(256) void k_scan2(const int* __restrict__ bsum, int* __restrict__ boff, int nb) {
    __shared__ int s[256];
    int v = (threadIdx.x < nb) ? bsum[threadIdx.x] : 0;
    s[threadIdx.x] = v;
    __syncthreads();
    #pragma unroll
    for (int off = 1; off < 256; off <<= 1) {
        int t = (threadIdx.x >= off) ? s[threadIdx.x - off] : 0;
        __syncthreads();
        s[threadIdx.x] += t;
        __syncthreads();
    }
    if (threadIdx.x < nb) boff[threadIdx.x] = s[threadIdx.x] - v;  // exclusive
}

__global__ __launch_bounds__(256) void k_scan3(const int* __restrict__ incl, const int* __restrict__ boff,
                                               const int* __restrict__ deg,
                                               int* __restrict__ offs, int* __restrict__ cursor, int n) {
    int i = blockIdx.x * 256 + threadIdx.x;
    if (i < n) {
        int inc = incl[i] + boff[blockIdx.x];
        offs[i + 1] = inc;
        cursor[i] = inc - deg[i];
    }
    if (i == 0) offs[0] = 0;
}

__global__ __launch_bounds__(256) void k_fill(const int* __restrict__ ei, int* __restrict__ cursor,
                                              int* __restrict__ esrc) {
    int e = blockIdx.x * 256 + threadIdx.x;
    if (e < NEDGES) {
        int dst = ei[NEDGES + e];
        int pos = atomicAdd(&cursor[dst], 1);
        esrc[pos] = ei[e];  // src = ei[0][e]
    }
}

// ---------------------------------------------------------------- mean aggregation (bf16 gather)
// one half-wave (32 lanes x ushort4 = full 256B bf16 row) per node; 8-edge unroll
__global__ __launch_bounds__(256) void k_aggregate(const unsigned short* __restrict__ hb,
                                                   const int* __restrict__ offs,
                                                   const int* __restrict__ esrc,
                                                   float* __restrict__ agg) {
    const int hw = threadIdx.x >> 5;
    const int lane = threadIdx.x & 31;
    const int node = blockIdx.x * 8 + hw;
    if (node >= NNODES) return;
    const int beg = offs[node];
    const int end = offs[node + 1];
    const int c4 = lane * 4;
    float4 a0 = {0.f, 0.f, 0.f, 0.f};
    float4 a1 = {0.f, 0.f, 0.f, 0.f};
    float4 a2 = {0.f, 0.f, 0.f, 0.f};
    float4 a3 = {0.f, 0.f, 0.f, 0.f};
    int e = beg;
    for (; e + 8 <= end; e += 8) {
        int s0 = esrc[e + 0], s1 = esrc[e + 1], s2 = esrc[e + 2], s3 = esrc[e + 3];
        int s4 = esrc[e + 4], s5 = esrc[e + 5], s6 = esrc[e + 6], s7 = esrc[e + 7];
        ushort4 v0 = *reinterpret_cast<const ushort4*>(&hb[s0 * D + c4]);
        ushort4 v1 = *reinterpret_cast<const ushort4*>(&hb[s1 * D + c4]);
        ushort4 v2 = *reinterpret_cast<const ushort4*>(&hb[s2 * D + c4]);
        ushort4 v3 = *reinterpret_cast<const ushort4*>(&hb[s3 * D + c4]);
        ushort4 v4 = *reinterpret_cast<const ushort4*>(&hb[s4 * D + c4]);
        ushort4 v5 = *reinterpret_cast<const ushort4*>(&hb[s5 * D + c4]);
        ushort4 v6 = *reinterpret_cast<const ushort4*>(&hb[s6 * D + c4]);
        ushort4 v7 = *reinterpret_cast<const ushort4*>(&hb[s7 * D + c4]);
        a0.x += bf2f(v0.x) + bf2f(v4.x); a0.y += bf2f(v0.y) + bf2f(v4.y);
        a0.z += bf2f(v0.z) + bf2f(v4.z); a0.w += bf2f(v0.w) + bf2f(v4.w);
        a1.x += bf2f(v1.x) + bf2f(v5.x); a1.y += bf2f(v1.y) + bf2f(v5.y);
        a1.z += bf2f(v1.z) + bf2f(v5.z); a1.w += bf2f(v1.w) + bf2f(v5.w);
        a2.x += bf2f(v2.x) + bf2f(v6.x); a2.y += bf2f(v2.y) + bf2f(v6.y);
        a2.z += bf2f(v2.z) + bf2f(v6.z); a2.w += bf2f(v2.w) + bf2f(v6.w);
        a3.x += bf2f(v3.x) + bf2f(v7.x); a3.y += bf2f(v3.y) + bf2f(v7.y);
        a3.z += bf2f(v3.z) + bf2f(v7.z); a3.w += bf2f(v3.w) + bf2f(v7.w);
    }
    for (; e + 4 <= end; e += 4) {
        int s0 = esrc[e + 0], s1 = esrc[e + 1], s2 = esrc[e + 2], s3 = esrc[e + 3];
        ushort4 v0 = *reinterpret_cast<const ushort4*>(&hb[s0 * D + c4]);
        ushort4 v1 = *reinterpret_cast<const ushort4*>(&hb[s1 * D + c4]);
        ushort4 v2 = *reinterpret_cast<const ushort4*>(&hb[s2 * D + c4]);
        ushort4 v3 = *reinterpret_cast<const ushort4*>(&hb[s3 * D + c4]);
        a0.x += bf2f(v0.x); a0.y += bf2f(v0.y); a0.z += bf2f(v0.z); a0.w += bf2f(v0.w);
        a1.x += bf2f(v1.x); a1.y += bf2f(v1.y); a1.z += bf2f(v1.z); a1.w += bf2f(v1.w);
        a2.x += bf2f(v2.x); a2.y += bf2f(v2.y); a2.z += bf2f(v2.z); a2.w += bf2f(v2.w);
        a3.x += bf2f(v3.x); a3.y += bf2f(v3.y); a3.z += bf2f(v3.z); a3.w += bf2f(v3.w);
    }
    for (; e < end; ++e) {
        int s0 = esrc[e];
        ushort4 v0 = *reinterpret_cast<const ushort4*>(&hb[s0 * D + c4]);
        a0.x += bf2f(v0.x); a0.y += bf2f(v0.y); a0.z += bf2f(v0.z); a0.w += bf2f(v0.w);
    }
    a0.x += a1.x + a2.x + a3.x;
    a0.y += a1.y + a2.y + a3.y;
    a0.z += a1.z + a2.z + a3.z;
    a0.w += a1.w + a2.w + a3.w;
    const int dg = end - beg;
    const float inv = 1.f / (float)(dg > 0 ? dg : 1);
    float4 o; o.x = a0.x * inv; o.y = a0.y * inv; o.z = a0.z * inv; o.w = a0.w * inv;
    *reinterpret_cast<float4*>(&agg[node * D + c4]) = o;
}

// ---------------------------------------------------------------- fused dual-GEMM + BN + ReLU (MFMA)
// C = [agg|hin] @ [Wl;Wr] as K=256; split-bf16 3-term (hi*hi + hi*lo + lo*hi)
// block: 256 threads = 4 waves in 2x2; wave computes 64x64 via 4x4 tiles of 16x16x32 MFMA
__global__ __launch_bounds__(256) void k_sage_gemm(const float* __restrict__ agg,
                                                   const float* __restrict__ hin,
                                                   const float* __restrict__ Wl,
                                                   const float* __restrict__ Wr,
                                                   const float* __restrict__ bl,
                                                   const float* __restrict__ gamma,
                                                   const float* __restrict__ beta,
                                                   const float* __restrict__ rmean,
                                                   const float* __restrict__ rvar,
                                                   float* __restrict__ hout,
                                                   unsigned short* __restrict__ houtb, int nrows) {
    __shared__ unsigned short Ah[128][40];  // [row][k] bf16 hi; stride 40 -> 2-way max conflicts
    __shared__ unsigned short Al[128][40];
    __shared__ unsigned short Bh[128][40];  // W transposed: [col][k]
    __shared__ unsigned short Bl[128][40];

    const int tid = threadIdx.x;
    const int wave = tid >> 6;
    const int lane = tid & 63;
    const int wr = wave >> 1, wc = wave & 1;
    const int l15 = lane & 15, l4 = lane >> 4;
    const int row0 = blockIdx.x * 128;

    f32x4 acc[4][4];
    #pragma unroll
    for (int mi = 0; mi < 4; ++mi)
        #pragma unroll
        for (int ni = 0; ni < 4; ++ni)
            acc[mi][ni] = (f32x4){0.f, 0.f, 0.f, 0.f};

    for (int kc = 0; kc < 8; ++kc) {
        const float* __restrict__ Asrc = (kc < 4) ? agg : hin;
        const float* __restrict__ Wsrc = (kc < 4) ? Wl : Wr;
        const int koff = (kc & 3) * 32;

        #pragma unroll
        for (int i = 0; i < 4; ++i) {
            int l = tid + i * 256;         // 0..1023
            int ar = l >> 3;               // row 0..127
            int kq = l & 7;                // k-quad
            int grow = row0 + ar;
            if (grow >= nrows) grow = nrows - 1;
            float4 v = *reinterpret_cast<const float4*>(&Asrc[grow * D + koff + kq * 4]);
            unsigned short h0 = f2bf_rne(v.x), h1 = f2bf_rne(v.y), h2 = f2bf_rne(v.z), h3 = f2bf_rne(v.w);
            unsigned short q0 = f2bf_rne(v.x - bf2f(h0)), q1 = f2bf_rne(v.y - bf2f(h1));
            unsigned short q2 = f2bf_rne(v.z - bf2f(h2)), q3 = f2bf_rne(v.w - bf2f(h3));
            short4v hs = {(short)h0, (short)h1, (short)h2, (short)h3};
            short4v qs = {(short)q0, (short)q1, (short)q2, (short)q3};
            *reinterpret_cast<short4v*>(&Ah[ar][kq * 4]) = hs;
            *reinterpret_cast<short4v*>(&Al[ar][kq * 4]) = qs;
        }
        #pragma unroll
        for (int i = 0; i < 4; ++i) {
            int l = tid + i * 256;         // 0..1023
            int wk = l >> 5;               // 0..31
            int wc4 = (l & 31) * 4;        // col base
            float4 v = *reinterpret_cast<const float4*>(&Wsrc[(koff + wk) * D + wc4]);
            unsigned short h0 = f2bf_rne(v.x), h1 = f2bf_rne(v.y), h2 = f2bf_rne(v.z), h3 = f2bf_rne(v.w);
            Bh[wc4 + 0][wk] = h0; Bl[wc4 + 0][wk] = f2bf_rne(v.x - bf2f(h0));
            Bh[wc4 + 1][wk] = h1; Bl[wc4 + 1][wk] = f2bf_rne(v.y - bf2f(h1));
            Bh[wc4 + 2][wk] = h2; Bl[wc4 + 2][wk] = f2bf_rne(v.z - bf2f(h2));
            Bh[wc4 + 3][wk] = h3; Bl[wc4 + 3][wk] = f2bf_rne(v.w - bf2f(h3));
        }
        __syncthreads();

        short8 bhf[4], blf[4];
        #pragma unroll
        for (int ni = 0; ni < 4; ++ni) {
            int c = wc * 64 + ni * 16 + l15;
            bhf[ni] = *reinterpret_cast<const short8*>(&Bh[c][l4 * 8]);
            blf[ni] = *reinterpret_cast<const short8*>(&Bl[c][l4 * 8]);
        }
        #pragma unroll
        for (int mi = 0; mi < 4; ++mi) {
            int r = wr * 64 + mi * 16 + l15;
            short8 ahf = *reinterpret_cast<const short8*>(&Ah[r][l4 * 8]);
            short8 alf = *reinterpret_cast<const short8*>(&Al[r][l4 * 8]);
            #pragma unroll
            for (int ni = 0; ni < 4; ++ni) {
                acc[mi][ni] = __builtin_amdgcn_mfma_f32_16x16x32_bf16(ahf, bhf[ni], acc[mi][ni], 0, 0, 0);
                acc[mi][ni] = __builtin_amdgcn_mfma_f32_16x16x32_bf16(ahf, blf[ni], acc[mi][ni], 0, 0, 0);
                acc[mi][ni] = __builtin_amdgcn_mfma_f32_16x16x32_bf16(alf, bhf[ni], acc[mi][ni], 0, 0, 0);
            }
        }
        __syncthreads();
    }

    // epilogue: + bl, BN(eval), ReLU; dual store fp32 + bf16 shadow
    float scn[4], shn[4];
    #pragma unroll
    for (int ni = 0; ni < 4; ++ni) {
        int c = wc * 64 + ni * 16 + l15;
        float s = gamma[c] * rsqrtf(rvar[c] + EPSBN);
        scn[ni] = s;
        shn[ni] = (bl[c] - rmean[c]) * s + beta[c];
    }
    #pragma unroll
    for (int mi = 0; mi < 4; ++mi) {
        #pragma unroll
        for (int ni = 0; ni < 4; ++ni) {
            int c = wc * 64 + ni * 16 + l15;
            #pragma unroll
            for (int j = 0; j < 4; ++j) {
                int grow = row0 + wr * 64 + mi * 16 + l4 * 4 + j;
                if (grow < nrows) {
                    float v = fmaxf(acc[mi][ni][j] * scn[ni] + shn[ni], 0.f);
                    hout[grow * D + c] = v;
                    if (houtb) houtb[grow * D + c] = f2bf_rne(v);
                }
            }
        }
    }
}

// ---------------------------------------------------------------- fused pool + MLP head
__global__ __launch_bounds__(128) void k_head(const float* __restrict__ h,
                                              const int* __restrict__ bidx,
                                              const float* __restrict__ W1,
                                              const float* __restrict__ b1,
                                              const float* __restrict__ W2,
                                              const float* __restrict__ b2,
                                              float* __restrict__ out) {
    __shared__ float gs[D];
    __shared__ float g1s[D];
    const int gid = blockIdx.x;
    const int t = threadIdx.x;
    int lo = 0, hi = NNODES;
    while (lo < hi) { int m = (lo + hi) >> 1; if (bidx[m] < gid) lo = m + 1; else hi = m; }
    const int s = lo;
    lo = s; hi = NNODES;
    while (lo < hi) { int m = (lo + hi) >> 1; if (bidx[m] < gid + 1) lo = m + 1; else hi = m; }
    const int e = lo;
    float acc = 0.f;
    int i = s;
    for (; i + 4 <= e; i += 4) {
        acc += h[(i + 0) * D + t] + h[(i + 1) * D + t]
             + h[(i + 2) * D + t] + h[(i + 3) * D + t];
    }
    for (; i < e; ++i) acc += h[i * D + t];
    const int c = e - s;
    gs[t] = acc / (float)(c > 0 ? c : 1);
    __syncthreads();
    float a1 = b1[t];
    #pragma unroll 8
    for (int k = 0; k < D; ++k) a1 += gs[k] * W1[k * D + t];
    g1s[t] = fmaxf(a1, 0.f);
    __syncthreads();
    if (t < NOUT) {
        float a2 = b2[t];
        #pragma unroll 8
        for (int k = 0; k < D; ++k) a2 += g1s[k] * W2[k * NOUT + t];
        out[gid * NOUT + t] = a2;
    }
}

// ---------------------------------------------------------------- launch
extern "C" void kernel_launch(void* const* d_in, const int* in_sizes, int n_in,
                              void* d_out, int out_size, void* d_ws, size_t ws_size,
                              hipStream_t stream) {
    const float* x     = (const float*)d_in[0];
    const int*   ei    = (const int*)d_in[1];
    const int*   b     = (const int*)d_in[2];
    const float* Wl    = (const float*)d_in[3];
    const float* bl    = (const float*)d_in[4];
    const float* Wr    = (const float*)d_in[5];
    const float* gamma = (const float*)d_in[6];
    const float* beta  = (const float*)d_in[7];
    const float* rmean = (const float*)d_in[8];
    const float* rvar  = (const float*)d_in[9];
    const float* W1    = (const float*)d_in[10];
    const float* b1    = (const float*)d_in[11];
    const float* W2    = (const float*)d_in[12];
    const float* b2    = (const float*)d_in[13];
    float* out = (float*)d_out;

    char* p = (char*)d_ws;
    auto take = [&](size_t bytes) { char* r = p; p += (bytes + 255) & ~size_t(255); return r; };
    float* h1   = (float*)take(sizeof(float) * NNODES * D);
    float* h2   = (float*)take(sizeof(float) * NNODES * D);
    float* agg  = (float*)take(sizeof(float) * NNODES * D);
    unsigned short* xb  = (unsigned short*)take(sizeof(unsigned short) * NNODES * D);
    unsigned short* hb1 = (unsigned short*)take(sizeof(unsigned short) * NNODES * D);
    unsigned short* hb2 = (unsigned short*)take(sizeof(unsigned short) * NNODES * D);
    int* esrc   = (int*)take(sizeof(int) * NEDGES);
    int* offs   = (int*)take(sizeof(int) * (NNODES + 1));
    int* cursor = (int*)take(sizeof(int) * NNODES);
    int* deg    = (int*)take(sizeof(int) * NNODES);
    int* incl   = (int*)take(sizeof(int) * NNODES);
    int* bsum   = (int*)take(sizeof(int) * 256);
    int* boff   = (int*)take(sizeof(int) * 256);

    const int NB_N = (NNODES + 255) / 256;    // 196
    const int NB_E = (NEDGES + 255) / 256;    // 3125

    // x -> bf16 shadow
    k_cvt_bf16<<<(NNODES * D / 4 + 255) / 256, 256, 0, stream>>>(x, xb, NNODES * D / 4);

    // CSR build
    k_zero_i32<<<NB_N, 256, 0, stream>>>(deg, NNODES);
    k_count<<<NB_E, 256, 0, stream>>>(ei, deg);
    k_scan1<<<NB_N, 256, 0, stream>>>(deg, incl, bsum, NNODES);
    k_scan2<<<1, 256, 0, stream>>>(bsum, boff, NB_N);
    k_scan3<<<NB_N, 256, 0, stream>>>(incl, boff, deg, offs, cursor, NNODES);
    k_fill<<<NB_E, 256, 0, stream>>>(ei, cursor, esrc);

    const int GB = (NNODES + 127) / 128;      // 391
    const float* hin = x;
    const unsigned short* hbin = xb;
    float* bufs[2] = {h1, h2};
    unsigned short* bbufs[2] = {hb1, hb2};
    for (int l = 0; l < 3; ++l) {
        float* hout = bufs[l & 1];
        unsigned short* houtb = (l < 2) ? bbufs[l & 1] : (unsigned short*)nullptr;
        k_aggregate<<<(NNODES + 7) / 8, 256, 0, stream>>>(hbin, offs, esrc, agg);
        k_sage_gemm<<<GB, 256, 0, stream>>>(agg, hin,
                                            Wl + (size_t)l * D * D, Wr + (size_t)l * D * D,
                                            bl + l * D, gamma + l * D, beta + l * D,
                                            rmean + l * D, rvar + l * D, hout, houtb, NNODES);
        hin = hout;
        hbin = bbufs[l & 1];
    }

    k_head<<<NGRAPH, 128, 0, stream>>>(hin, b, W1, b1, W2, b2, out);
}

// Round 11
// 362.412 us; speedup vs baseline: 2.3153x; 1.2185x over previous
//
#include <hip/hip_runtime.h>

#define D 128
#define NNODES 50000
#define NEDGES 800000
#define NGRAPH 512
#define NOUT 64
#define EPSBN 1e-5f

typedef __attribute__((ext_vector_type(8))) short short8;
typedef __attribute__((ext_vector_type(4))) short short4v;
typedef __attribute__((ext_vector_type(4))) float f32x4;

__device__ inline unsigned short f2bf_rne(float x) {
    unsigned u = __float_as_uint(x);
    unsigned r = (u + 0x7FFFu + ((u >> 16) & 1u)) >> 16;
    return (unsigned short)r;
}
__device__ inline float bf2f(unsigned short h) { return __uint_as_float(((unsigned)h) << 16); }

// ---------------------------------------------------------------- utilities
__global__ __launch_bounds__(256) void k_zero_i32(int* __restrict__ p, int n) {
    int i = blockIdx.x * 256 + threadIdx.x;
    if (i < n) p[i] = 0;
}

// x (fp32) -> xb (bf16)
__global__ __launch_bounds__(256) void k_cvt_bf16(const float* __restrict__ x,
                                                  unsigned short* __restrict__ xb, int n4) {
    int i = blockIdx.x * 256 + threadIdx.x;
    if (i < n4) {
        float4 v = *reinterpret_cast<const float4*>(&x[i * 4]);
        ushort4 o;
        o.x = f2bf_rne(v.x); o.y = f2bf_rne(v.y); o.z = f2bf_rne(v.z); o.w = f2bf_rne(v.w);
        *reinterpret_cast<ushort4*>(&xb[i * 4]) = o;
    }
}

// W -> transposed split-bf16: wt[layer][col][k], k in [0,256): k<128 from Wl, else Wr
__global__ __launch_bounds__(256) void k_prep_w(const float* __restrict__ Wl,
                                                const float* __restrict__ Wr,
                                                unsigned short* __restrict__ wt_hi,
                                                unsigned short* __restrict__ wt_lo) {
    int idx = blockIdx.x * 256 + threadIdx.x;       // [l][c][k], 3*128*256
    int l = idx >> 15;
    int rem = idx & 32767;
    int c = rem >> 8;
    int k = rem & 255;
    float v = (k < 128) ? Wl[l * 16384 + k * 128 + c]
                        : Wr[l * 16384 + (k - 128) * 128 + c];
    unsigned short h = f2bf_rne(v);
    wt_hi[idx] = h;
    wt_lo[idx] = f2bf_rne(v - bf2f(h));
}

// ---------------------------------------------------------------- CSR build
__global__ __launch_bounds__(256) void k_count(const int* __restrict__ ei, int* __restrict__ deg) {
    int e = blockIdx.x * 256 + threadIdx.x;
    if (e < NEDGES) atomicAdd(&deg[ei[NEDGES + e]], 1);  // dst = ei[1][e]
}

__global__ __launch_bounds__(256) void k_scan1(const int* __restrict__ deg, int* __restrict__ incl,
                                               int* __restrict__ bsum, int n) {
    __shared__ int s[256];
    int i = blockIdx.x * 256 + threadIdx.x;
    int v = (i < n) ? deg[i] : 0;
    s[threadIdx.x] = v;
    __syncthreads();
    #pragma unroll
    for (int off = 1; off < 256; off <<= 1) {
        int t = (threadIdx.x >= off) ? s[threadIdx.x - off] : 0;
        __syncthreads();
        s[threadIdx.x] += t;
        __syncthreads();
    }
    if (i < n) incl[i] = s[threadIdx.x];
    if (threadIdx.x == 255) bsum[blockIdx.x] = s[255];
}

__global__ __launch_bounds__(256) void k_scan2(const int* __restrict__ bsum, int* __restrict__ boff, int nb) {
    __shared__ int s[256];
    int v = (threadIdx.x < nb) ? bsum[threadIdx.x] : 0;
    s[threadIdx.x] = v;
    __syncthreads();
    #pragma unroll
    for (int off = 1; off < 256; off <<= 1) {
        int t = (threadIdx.x >= off) ? s[threadIdx.x - off] : 0;
        __syncthreads();
        s[threadIdx.x] += t;
        __syncthreads();
    }
    if (threadIdx.x < nb) boff[threadIdx.x] = s[threadIdx.x] - v;  // exclusive
}

__global__ __launch_bounds__(256) void k_scan3(const int* __restrict__ incl, const int* __restrict__ boff,
                                               const int* __restrict__ deg,
                                               int* __restrict__ offs, int* __restrict__ cursor, int n) {
    int i = blockIdx.x * 256 + threadIdx.x;
    if (i < n) {
        int inc = incl[i] + boff[blockIdx.x];
        offs[i + 1] = inc;
        cursor[i] = inc - deg[i];
    }
    if (i == 0) offs[0] = 0;
}

__global__ __launch_bounds__(256) void k_fill(const int* __restrict__ ei, int* __restrict__ cursor,
                                              int* __restrict__ esrc) {
    int e = blockIdx.x * 256 + threadIdx.x;
    if (e < NEDGES) {
        int dst = ei[NEDGES + e];
        int pos = atomicAdd(&cursor[dst], 1);
        esrc[pos] = ei[e];  // src = ei[0][e]
    }
}

// ---------------------------------------------------------------- mean aggregation (bf16 gather)
__global__ __launch_bounds__(256) void k_aggregate(const unsigned short* __restrict__ hb,
                                                   const int* __restrict__ offs,
                                                   const int* __restrict__ esrc,
                                                   float* __restrict__ agg) {
    const int hw = threadIdx.x >> 5;
    const int lane = threadIdx.x & 31;
    const int node = blockIdx.x * 8 + hw;
    if (node >= NNODES) return;
    const int beg = offs[node];
    const int end = offs[node + 1];
    const int c4 = lane * 4;
    float4 a0 = {0.f, 0.f, 0.f, 0.f};
    float4 a1 = {0.f, 0.f, 0.f, 0.f};
    float4 a2 = {0.f, 0.f, 0.f, 0.f};
    float4 a3 = {0.f, 0.f, 0.f, 0.f};
    int e = beg;
    for (; e + 8 <= end; e += 8) {
        int s0 = esrc[e + 0], s1 = esrc[e + 1], s2 = esrc[e + 2], s3 = esrc[e + 3];
        int s4 = esrc[e + 4], s5 = esrc[e + 5], s6 = esrc[e + 6], s7 = esrc[e + 7];
        ushort4 v0 = *reinterpret_cast<const ushort4*>(&hb[s0 * D + c4]);
        ushort4 v1 = *reinterpret_cast<const ushort4*>(&hb[s1 * D + c4]);
        ushort4 v2 = *reinterpret_cast<const ushort4*>(&hb[s2 * D + c4]);
        ushort4 v3 = *reinterpret_cast<const ushort4*>(&hb[s3 * D + c4]);
        ushort4 v4 = *reinterpret_cast<const ushort4*>(&hb[s4 * D + c4]);
        ushort4 v5 = *reinterpret_cast<const ushort4*>(&hb[s5 * D + c4]);
        ushort4 v6 = *reinterpret_cast<const ushort4*>(&hb[s6 * D + c4]);
        ushort4 v7 = *reinterpret_cast<const ushort4*>(&hb[s7 * D + c4]);
        a0.x += bf2f(v0.x) + bf2f(v4.x); a0.y += bf2f(v0.y) + bf2f(v4.y);
        a0.z += bf2f(v0.z) + bf2f(v4.z); a0.w += bf2f(v0.w) + bf2f(v4.w);
        a1.x += bf2f(v1.x) + bf2f(v5.x); a1.y += bf2f(v1.y) + bf2f(v5.y);
        a1.z += bf2f(v1.z) + bf2f(v5.z); a1.w += bf2f(v1.w) + bf2f(v5.w);
        a2.x += bf2f(v2.x) + bf2f(v6.x); a2.y += bf2f(v2.y) + bf2f(v6.y);
        a2.z += bf2f(v2.z) + bf2f(v6.z); a2.w += bf2f(v2.w) + bf2f(v6.w);
        a3.x += bf2f(v3.x) + bf2f(v7.x); a3.y += bf2f(v3.y) + bf2f(v7.y);
        a3.z += bf2f(v3.z) + bf2f(v7.z); a3.w += bf2f(v3.w) + bf2f(v7.w);
    }
    for (; e + 4 <= end; e += 4) {
        int s0 = esrc[e + 0], s1 = esrc[e + 1], s2 = esrc[e + 2], s3 = esrc[e + 3];
        ushort4 v0 = *reinterpret_cast<const ushort4*>(&hb[s0 * D + c4]);
        ushort4 v1 = *reinterpret_cast<const ushort4*>(&hb[s1 * D + c4]);
        ushort4 v2 = *reinterpret_cast<const ushort4*>(&hb[s2 * D + c4]);
        ushort4 v3 = *reinterpret_cast<const ushort4*>(&hb[s3 * D + c4]);
        a0.x += bf2f(v0.x); a0.y += bf2f(v0.y); a0.z += bf2f(v0.z); a0.w += bf2f(v0.w);
        a1.x += bf2f(v1.x); a1.y += bf2f(v1.y); a1.z += bf2f(v1.z); a1.w += bf2f(v1.w);
        a2.x += bf2f(v2.x); a2.y += bf2f(v2.y); a2.z += bf2f(v2.z); a2.w += bf2f(v2.w);
        a3.x += bf2f(v3.x); a3.y += bf2f(v3.y); a3.z += bf2f(v3.z); a3.w += bf2f(v3.w);
    }
    for (; e < end; ++e) {
        int s0 = esrc[e];
        ushort4 v0 = *reinterpret_cast<const ushort4*>(&hb[s0 * D + c4]);
        a0.x += bf2f(v0.x); a0.y += bf2f(v0.y); a0.z += bf2f(v0.z); a0.w += bf2f(v0.w);
    }
    a0.x += a1.x + a2.x + a3.x;
    a0.y += a1.y + a2.y + a3.y;
    a0.z += a1.z + a2.z + a3.z;
    a0.w += a1.w + a2.w + a3.w;
    const int dg = end - beg;
    const float inv = 1.f / (float)(dg > 0 ? dg : 1);
    float4 o; o.x = a0.x * inv; o.y = a0.y * inv; o.z = a0.z * inv; o.w = a0.w * inv;
    *reinterpret_cast<float4*>(&agg[node * D + c4]) = o;
}

// ---------------------------------------------------------------- fused dual-GEMM + BN + ReLU (MFMA)
// C = [agg|hin] @ Wt^T, K=256; split-bf16 3-term; W pre-transposed+split in global.
// block: 256 threads = 4 waves in 2x2; wave computes 64x64 via 4x4 tiles of 16x16x32 MFMA
__global__ __launch_bounds__(256) void k_sage_gemm(const float* __restrict__ agg,
                                                   const float* __restrict__ hin,
                                                   const unsigned short* __restrict__ wt_hi,
                                                   const unsigned short* __restrict__ wt_lo,
                                                   const float* __restrict__ bl,
                                                   const float* __restrict__ gamma,
                                                   const float* __restrict__ beta,
                                                   const float* __restrict__ rmean,
                                                   const float* __restrict__ rvar,
                                                   float* __restrict__ hout,
                                                   unsigned short* __restrict__ houtb, int nrows) {
    __shared__ unsigned short Ah[128][40];  // [row][k]; stride 40 shorts = 80B = 5x16B (b128-aligned)
    __shared__ unsigned short Al[128][40];
    __shared__ unsigned short Bh[128][40];  // [col][k]
    __shared__ unsigned short Bl[128][40];

    const int tid = threadIdx.x;
    const int wave = tid >> 6;
    const int lane = tid & 63;
    const int wr = wave >> 1, wc = wave & 1;
    const int l15 = lane & 15, l4 = lane >> 4;
    const int row0 = blockIdx.x * 128;

    f32x4 acc[4][4];
    #pragma unroll
    for (int mi = 0; mi < 4; ++mi)
        #pragma unroll
        for (int ni = 0; ni < 4; ++ni)
            acc[mi][ni] = (f32x4){0.f, 0.f, 0.f, 0.f};

    for (int kc = 0; kc < 8; ++kc) {
        const float* __restrict__ Asrc = (kc < 4) ? agg : hin;
        const int koff = kc * 32;               // global k 0..255
        const int akoff = (kc & 3) * 32;        // within source matrix

        // stage A: 128 rows x 32 k; each thread 8 floats -> split -> short8 (b128 writes)
        #pragma unroll
        for (int i = 0; i < 2; ++i) {
            int l = tid + i * 256;              // 0..511
            int ar = l >> 2;                    // row 0..127
            int ko = (l & 3) * 8;               // k-octet base
            int grow = row0 + ar;
            if (grow >= nrows) grow = nrows - 1;
            const float* src = &Asrc[grow * D + akoff + ko];
            float4 va = *reinterpret_cast<const float4*>(src);
            float4 vb = *reinterpret_cast<const float4*>(src + 4);
            unsigned short h0 = f2bf_rne(va.x), h1 = f2bf_rne(va.y), h2 = f2bf_rne(va.z), h3 = f2bf_rne(va.w);
            unsigned short h4 = f2bf_rne(vb.x), h5 = f2bf_rne(vb.y), h6 = f2bf_rne(vb.z), h7 = f2bf_rne(vb.w);
            short8 hs = {(short)h0, (short)h1, (short)h2, (short)h3,
                         (short)h4, (short)h5, (short)h6, (short)h7};
            short8 qs = {(short)f2bf_rne(va.x - bf2f(h0)), (short)f2bf_rne(va.y - bf2f(h1)),
                         (short)f2bf_rne(va.z - bf2f(h2)), (short)f2bf_rne(va.w - bf2f(h3)),
                         (short)f2bf_rne(vb.x - bf2f(h4)), (short)f2bf_rne(vb.y - bf2f(h5)),
                         (short)f2bf_rne(vb.z - bf2f(h6)), (short)f2bf_rne(vb.w - bf2f(h7))};
            *reinterpret_cast<short8*>(&Ah[ar][ko]) = hs;
            *reinterpret_cast<short8*>(&Al[ar][ko]) = qs;
        }
        // stage B: pure vector copy from pre-transposed split W
        #pragma unroll
        for (int i = 0; i < 2; ++i) {
            int l = tid + i * 256;              // 0..511
            int col = l >> 2;                   // 0..127
            int ko = (l & 3) * 8;
            *reinterpret_cast<short8*>(&Bh[col][ko]) =
                *reinterpret_cast<const short8*>(&wt_hi[col * 256 + koff + ko]);
            *reinterpret_cast<short8*>(&Bl[col][ko]) =
                *reinterpret_cast<const short8*>(&wt_lo[col * 256 + koff + ko]);
        }
        __syncthreads();

        short8 bhf[4], blf[4];
        #pragma unroll
        for (int ni = 0; ni < 4; ++ni) {
            int c = wc * 64 + ni * 16 + l15;
            bhf[ni] = *reinterpret_cast<const short8*>(&Bh[c][l4 * 8]);
            blf[ni] = *reinterpret_cast<const short8*>(&Bl[c][l4 * 8]);
        }
        #pragma unroll
        for (int mi = 0; mi < 4; ++mi) {
            int r = wr * 64 + mi * 16 + l15;
            short8 ahf = *reinterpret_cast<const short8*>(&Ah[r][l4 * 8]);
            short8 alf = *reinterpret_cast<const short8*>(&Al[r][l4 * 8]);
            #pragma unroll
            for (int ni = 0; ni < 4; ++ni) {
                acc[mi][ni] = __builtin_amdgcn_mfma_f32_16x16x32_bf16(ahf, bhf[ni], acc[mi][ni], 0, 0, 0);
                acc[mi][ni] = __builtin_amdgcn_mfma_f32_16x16x32_bf16(ahf, blf[ni], acc[mi][ni], 0, 0, 0);
                acc[mi][ni] = __builtin_amdgcn_mfma_f32_16x16x32_bf16(alf, bhf[ni], acc[mi][ni], 0, 0, 0);
            }
        }
        __syncthreads();
    }

    // epilogue: + bl, BN(eval), ReLU; dual store fp32 + bf16 shadow
    float scn[4], shn[4];
    #pragma unroll
    for (int ni = 0; ni < 4; ++ni) {
        int c = wc * 64 + ni * 16 + l15;
        float s = gamma[c] * rsqrtf(rvar[c] + EPSBN);
        scn[ni] = s;
        shn[ni] = (bl[c] - rmean[c]) * s + beta[c];
    }
    #pragma unroll
    for (int mi = 0; mi < 4; ++mi) {
        #pragma unroll
        for (int ni = 0; ni < 4; ++ni) {
            int c = wc * 64 + ni * 16 + l15;
            #pragma unroll
            for (int j = 0; j < 4; ++j) {
                int grow = row0 + wr * 64 + mi * 16 + l4 * 4 + j;
                if (grow < nrows) {
                    float v = fmaxf(acc[mi][ni][j] * scn[ni] + shn[ni], 0.f);
                    hout[grow * D + c] = v;
                    if (houtb) houtb[grow * D + c] = f2bf_rne(v);
                }
            }
        }
    }
}

// ---------------------------------------------------------------- fused pool + MLP head
__global__ __launch_bounds__(128) void k_head(const float* __restrict__ h,
                                              const int* __restrict__ bidx,
                                              const float* __restrict__ W1,
                                              const float* __restrict__ b1,
                                              const float* __restrict__ W2,
                                              const float* __restrict__ b2,
                                              float* __restrict__ out) {
    __shared__ float gs[D];
    __shared__ float g1s[D];
    const int gid = blockIdx.x;
    const int t = threadIdx.x;
    int lo = 0, hi = NNODES;
    while (lo < hi) { int m = (lo + hi) >> 1; if (bidx[m] < gid) lo = m + 1; else hi = m; }
    const int s = lo;
    lo = s; hi = NNODES;
    while (lo < hi) { int m = (lo + hi) >> 1; if (bidx[m] < gid + 1) lo = m + 1; else hi = m; }
    const int e = lo;
    float acc = 0.f;
    int i = s;
    for (; i + 4 <= e; i += 4) {
        acc += h[(i + 0) * D + t] + h[(i + 1) * D + t]
             + h[(i + 2) * D + t] + h[(i + 3) * D + t];
    }
    for (; i < e; ++i) acc += h[i * D + t];
    const int c = e - s;
    gs[t] = acc / (float)(c > 0 ? c : 1);
    __syncthreads();
    float a1 = b1[t];
    #pragma unroll 8
    for (int k = 0; k < D; ++k) a1 += gs[k] * W1[k * D + t];
    g1s[t] = fmaxf(a1, 0.f);
    __syncthreads();
    if (t < NOUT) {
        float a2 = b2[t];
        #pragma unroll 8
        for (int k = 0; k < D; ++k) a2 += g1s[k] * W2[k * NOUT + t];
        out[gid * NOUT + t] = a2;
    }
}

// ---------------------------------------------------------------- launch
extern "C" void kernel_launch(void* const* d_in, const int* in_sizes, int n_in,
                              void* d_out, int out_size, void* d_ws, size_t ws_size,
                              hipStream_t stream) {
    const float* x     = (const float*)d_in[0];
    const int*   ei    = (const int*)d_in[1];
    const int*   b     = (const int*)d_in[2];
    const float* Wl    = (const float*)d_in[3];
    const float* bl    = (const float*)d_in[4];
    const float* Wr    = (const float*)d_in[5];
    const float* gamma = (const float*)d_in[6];
    const float* beta  = (const float*)d_in[7];
    const float* rmean = (const float*)d_in[8];
    const float* rvar  = (const float*)d_in[9];
    const float* W1    = (const float*)d_in[10];
    const float* b1    = (const float*)d_in[11];
    const float* W2    = (const float*)d_in[12];
    const float* b2    = (const float*)d_in[13];
    float* out = (float*)d_out;

    char* p = (char*)d_ws;
    auto take = [&](size_t bytes) { char* r = p; p += (bytes + 255) & ~size_t(255); return r; };
    float* h1   = (float*)take(sizeof(float) * NNODES * D);
    float* h2   = (float*)take(sizeof(float) * NNODES * D);
    float* agg  = (float*)take(sizeof(float) * NNODES * D);
    unsigned short* xb  = (unsigned short*)take(sizeof(unsigned short) * NNODES * D);
    unsigned short* hb1 = (unsigned short*)take(sizeof(unsigned short) * NNODES * D);
    unsigned short* hb2 = (unsigned short*)take(sizeof(unsigned short) * NNODES * D);
    unsigned short* wt_hi = (unsigned short*)take(sizeof(unsigned short) * 3 * 128 * 256);
    unsigned short* wt_lo = (unsigned short*)take(sizeof(unsigned short) * 3 * 128 * 256);
    int* esrc   = (int*)take(sizeof(int) * NEDGES);
    int* offs   = (int*)take(sizeof(int) * (NNODES + 1));
    int* cursor = (int*)take(sizeof(int) * NNODES);
    int* deg    = (int*)take(sizeof(int) * NNODES);
    int* incl   = (int*)take(sizeof(int) * NNODES);
    int* bsum   = (int*)take(sizeof(int) * 256);
    int* boff   = (int*)take(sizeof(int) * 256);

    const int NB_N = (NNODES + 255) / 256;    // 196
    const int NB_E = (NEDGES + 255) / 256;    // 3125

    // weight prep + x shadow
    k_prep_w<<<(3 * 128 * 256) / 256, 256, 0, stream>>>(Wl, Wr, wt_hi, wt_lo);
    k_cvt_bf16<<<(NNODES * D / 4 + 255) / 256, 256, 0, stream>>>(x, xb, NNODES * D / 4);

    // CSR build
    k_zero_i32<<<NB_N, 256, 0, stream>>>(deg, NNODES);
    k_count<<<NB_E, 256, 0, stream>>>(ei, deg);
    k_scan1<<<NB_N, 256, 0, stream>>>(deg, incl, bsum, NNODES);
    k_scan2<<<1, 256, 0, stream>>>(bsum, boff, NB_N);
    k_scan3<<<NB_N, 256, 0, stream>>>(incl, boff, deg, offs, cursor, NNODES);
    k_fill<<<NB_E, 256, 0, stream>>>(ei, cursor, esrc);

    const int GB = (NNODES + 127) / 128;      // 391
    const float* hin = x;
    const unsigned short* hbin = xb;
    float* bufs[2] = {h1, h2};
    unsigned short* bbufs[2] = {hb1, hb2};
    for (int l = 0; l < 3; ++l) {
        float* hout = bufs[l & 1];
        unsigned short* houtb = (l < 2) ? bbufs[l & 1] : (unsigned short*)nullptr;
        k_aggregate<<<(NNODES + 7) / 8, 256, 0, stream>>>(hbin, offs, esrc, agg);
        k_sage_gemm<<<GB, 256, 0, stream>>>(agg, hin,
                                            wt_hi + (size_t)l * 32768, wt_lo + (size_t)l * 32768,
                                            bl + l * D, gamma + l * D, beta + l * D,
                                            rmean + l * D, rvar + l * D, hout, houtb, NNODES);
        hin = hout;
        hbin = bbufs[l & 1];
    }

    k_head<<<NGRAPH, 128, 0, stream>>>(hin, b, W1, b1, W2, b2, out);
}